// Round 6
// baseline (103.436 us; speedup 1.0000x reference)
//
#include <hip/hip_runtime.h>
#include <hip/hip_fp16.h>

// GEMM view: Out[(b,d), c] = sum_k A[(b,d),k] * Bk[k,c]
//   row = b*32+d (M=131072), k = i*32+j (K=1024), col = c (N=64)
// A[(b,d), i*32+j] = x[b,i,d] * y[b,j,d] — rank-1, built in regs (f16 path).
// R6: K-split waves. Wave = 2b x full C x half-K (16 MFMA steps) -> 4096
// waves = 4 waves/SIMD, A built once per row, B read straight from L2
// (no K-loop barriers). K-half accs combined via 32 KB LDS (unioned with
// dead x-stage buffer). Grid 1024 x 256, 4 blocks/CU.

typedef __attribute__((ext_vector_type(8))) _Float16 half8;   // MFMA operand
typedef __attribute__((ext_vector_type(2))) __fp16 fp16x2;    // cvt_pkrtz/pk_mul
typedef __attribute__((ext_vector_type(4))) float f32x4;
typedef __attribute__((ext_vector_type(8))) short short8;

__device__ __forceinline__ unsigned int dup_h(float f) {
    union { fp16x2 h; unsigned int u; } w;
    w.h = __builtin_amdgcn_cvt_pkrtz(f, f);
    return w.u;
}
__device__ __forceinline__ fp16x2 pk2(float a, float b) {
    return __builtin_amdgcn_cvt_pkrtz(a, b);
}

// kswz f16 frag order: g = (s*4+nt)*64 + lane,
// kswz[g*8+t] = f16(kernel[c = nt*16+(lane&15)][s][(lane>>4)*8 + t])
__global__ __launch_bounds__(256) void kswz_kernel(const float* __restrict__ kern,
                                                   unsigned short* __restrict__ kswz) {
    int idx  = blockIdx.x * 256 + threadIdx.x;  // 8192
    int lane = idx & 63;
    int nt   = (idx >> 6) & 3;
    int s    = idx >> 8;
    int c    = nt * 16 + (lane & 15);
    int jb   = (lane >> 4) * 8;
    const float* src = kern + c * 1024 + s * 32 + jb;
    union { half8 h; short8 s8; } v;
#pragma unroll
    for (int t = 0; t < 8; ++t) v.h[t] = (_Float16)src[t];  // RNE
    *(short8*)(kswz + (size_t)idx * 8) = v.s8;
}

__global__ __launch_bounds__(256, 4) void cin_main(const float* __restrict__ x,
                                                   const float* __restrict__ y,
                                                   const unsigned short* __restrict__ kswz,
                                                   float* __restrict__ out_mat,
                                                   float* __restrict__ out_fin) {
    // 32 KB shared: first 16 KB = dup'd-f16 x stage (K-loop);
    // whole 32 KB reused as the K-half reduction buffer (epilogue).
    __shared__ __align__(16) unsigned char smem[32768];
    unsigned int* xs = (unsigned int*)smem;
    f32x4* red = (f32x4*)smem;

    const int tid  = threadIdx.x;
    const int wave = tid >> 6;        // 0..3
    const int lane = tid & 63;
    const int quad = lane >> 4;
    const int n16  = lane & 15;
    const int bpair = wave & 1;       // which 2 b's
    const int khalf = wave >> 1;      // which K half
    const int b_blk = blockIdx.x * 4;
    const int b0 = b_blk + bpair * 2;

    // ---- stage x (4 b's) as dup'd f16 pairs: xs[b_loc*1024 + i*32 + d] ----
    {
        const float4* xg4 = (const float4*)(x + (size_t)b_blk * 1024);
#pragma unroll
        for (int r = 0; r < 4; ++r) {
            int i4 = r * 256 + tid;   // 1024 float4 per block
            float4 v = xg4[i4];
            uint4 w;
            w.x = dup_h(v.x); w.y = dup_h(v.y); w.z = dup_h(v.z); w.w = dup_h(v.w);
            *(uint4*)&xs[i4 * 4] = w;
        }
    }

    // ---- y fragments as packed f16 pairs (j range indep. of K half) ----
    fp16x2 yv2[4][4];
#pragma unroll
    for (int mt = 0; mt < 4; ++mt) {
        const int b = b0 + (mt >> 1);
        const int d = n16 + 16 * (mt & 1);
        const float* yp = y + (size_t)b * 1024 + (quad * 8) * 32 + d;
#pragma unroll
        for (int p = 0; p < 4; ++p)
            yv2[mt][p] = pk2(yp[(2 * p) * 32], yp[(2 * p + 1) * 32]);
    }

    f32x4 acc[4][4];
#pragma unroll
    for (int mt = 0; mt < 4; ++mt)
#pragma unroll
        for (int nt = 0; nt < 4; ++nt) acc[mt][nt] = (f32x4){0.f, 0.f, 0.f, 0.f};

    int xoff[4];
#pragma unroll
    for (int mt = 0; mt < 4; ++mt)
        xoff[mt] = (bpair * 2 + (mt >> 1)) * 1024 + n16 + 16 * (mt & 1);

    const char* kl = (const char*)kswz + lane * 16;  // + s*4096 + nt*1024
    const int rot = blockIdx.x & 15;                 // de-lockstep L2 stream

    __syncthreads();

    // ---- K-loop: 16 steps, no barriers, B straight from L2 ----
#pragma unroll
    for (int k = 0; k < 16; ++k) {
        const int s = khalf * 16 + ((k + rot) & 15);
        half8 bf[4];
#pragma unroll
        for (int nt = 0; nt < 4; ++nt)
            bf[nt] = *(const half8*)(kl + s * 4096 + nt * 1024);
#pragma unroll
        for (int mt = 0; mt < 4; ++mt) {
            union { unsigned int u; fp16x2 h; } xv;
            xv.u = xs[xoff[mt] + s * 32];
            union { half8 h8; fp16x2 h2[4]; } af;
#pragma unroll
            for (int p = 0; p < 4; ++p) af.h2[p] = xv.h * yv2[mt][p];  // v_pk_mul_f16
#pragma unroll
            for (int nt = 0; nt < 4; ++nt)
                acc[mt][nt] = __builtin_amdgcn_mfma_f32_16x16x32_f16(
                    af.h8, bf[nt], acc[mt][nt], 0, 0, 0);
        }
    }

    // ---- combine K halves via LDS (xs is dead now) ----
    __syncthreads();
    if (khalf == 1) {
#pragma unroll
        for (int mt = 0; mt < 4; ++mt)
#pragma unroll
            for (int nt = 0; nt < 4; ++nt)
                red[(bpair * 16 + mt * 4 + nt) * 64 + lane] = acc[mt][nt];
    }
    __syncthreads();
    if (khalf == 0) {
#pragma unroll
        for (int mt = 0; mt < 4; ++mt)
#pragma unroll
            for (int nt = 0; nt < 4; ++nt) {
                f32x4 o = red[(bpair * 16 + mt * 4 + nt) * 64 + lane];
                acc[mt][nt] += o;
            }

        // ---- epilogue: output_mat[b][c][d], d = 16*(mt&1) + quad*4 + t ----
#pragma unroll
        for (int mt = 0; mt < 4; ++mt) {
            const int b = b0 + (mt >> 1);
            const int dbase = 16 * (mt & 1) + quad * 4;
#pragma unroll
            for (int nt = 0; nt < 4; ++nt) {
                const int c = nt * 16 + n16;
                *(f32x4*)(out_mat + (size_t)b * 2048 + c * 32 + dbase) = acc[mt][nt];
            }
        }

        // ---- final_output[b][c] = sum_d output_mat[b][c][d] ----
#pragma unroll
        for (int a = 0; a < 2; ++a) {
            const int b = b0 + a;
#pragma unroll
            for (int nt = 0; nt < 4; ++nt) {
                float f = 0.f;
#pragma unroll
                for (int t = 0; t < 4; ++t) f += acc[2 * a][nt][t] + acc[2 * a + 1][nt][t];
                f += __shfl_xor(f, 16);
                f += __shfl_xor(f, 32);
                if (lane < 16) out_fin[(size_t)b * 64 + nt * 16 + n16] = f;
            }
        }
    }
}

extern "C" void kernel_launch(void* const* d_in, const int* in_sizes, int n_in,
                              void* d_out, int out_size, void* d_ws, size_t ws_size,
                              hipStream_t stream) {
    const float* x    = (const float*)d_in[0];   // [4096,32,32]
    const float* y    = (const float*)d_in[1];   // [4096,32,32]
    const float* kern = (const float*)d_in[2];   // [64,32,32]
    float* out_mat = (float*)d_out;                      // [4096,64,32]
    float* out_fin = (float*)d_out + 4096 * 64 * 32;     // [4096,64]
    unsigned short* kswz = (unsigned short*)d_ws;        // 65536 f16 = 128 KB

    kswz_kernel<<<32, 256, 0, stream>>>(kern, kswz);
    cin_main<<<1024, 256, 0, stream>>>(x, y, kswz, out_mat, out_fin);
}